// Round 4
// baseline (194.056 us; speedup 1.0000x reference)
//
#include <hip/hip_runtime.h>
#include <cstdint>
#include <cstddef>

#define NB   8
#define CIN  128
#define COUT 64
#define LOG2E 1.44269504088896340736f

typedef _Float16 f16;
typedef _Float16 half4_t __attribute__((ext_vector_type(4)));
typedef _Float16 half8_t __attribute__((ext_vector_type(8)));
typedef short    bs8    __attribute__((ext_vector_type(8)));  // bf16x8 frag (bit pattern)
typedef float    float4_t __attribute__((ext_vector_type(4)));
typedef unsigned int uint2_t __attribute__((ext_vector_type(2)));

// float -> bf16 bits, RNE
__device__ __forceinline__ unsigned short f2bf(float f){
  unsigned u = __float_as_uint(f);
  return (unsigned short)((u + 0x7fffu + ((u >> 16) & 1u)) >> 16);
}

// ============ Fully fused: 1x1 convs (Q/K/V in LDS) + flash local attention ============
// 512 blocks x 512 threads (8 waves), 2 blocks/CU (LDS 64.5 KB). Block = image n (b&7,
// = XCD) x row pair (h0, h0+2). No workspace: K/V rows conv'd on the fly into LDS
// (5x redundant MFMA, ~cheap), Q conv'd in prologue. Attention math identical to the
// verified 2-kernel version (row-paired, NO-MAX exp2 softmax); K/V halos zeroed in LDS
// replace the old masked global-overrun trick.
__global__ __launch_bounds__(512, 4) void fused_k(
    const float* __restrict__ x, const float* __restrict__ W1,
    const float* __restrict__ W2, const float* __restrict__ W3,
    float* __restrict__ out)
{
  // LDS map (64512 B total):
  //   xs   [64][136] f16   @ 0      (17408)  x-chunk staging
  //   Kl   [8][144][8] f16 @ 17408  (18432)  K row, Ki-interleaved, px+8 halo
  //   Vl   [64][144] u16   @ 35840  (18432)  V row, planar bf16, px+8 halo
  //   plds [8][640] u16    @ 54272  (10240)  per-wave P staging (shared row0/row1)
  //   Ql   [8][128][8] f16 @ 35840  (alias over Vl; prologue only)
  __shared__ __align__(16) unsigned char smem[64512];
  f16* xs = (f16*)smem;
  f16* Kl = (f16*)(smem + 17408);
  unsigned short* Vl = (unsigned short*)(smem + 35840);
  unsigned short* plds = (unsigned short*)(smem + 54272);
  f16* Ql = (f16*)(smem + 35840);

  int tid = threadIdx.x, lane = tid & 63, wv = tid >> 6;
  int l15 = lane & 15, q4 = lane >> 4;
  int b = blockIdx.x;
  int n = b & 7;                                  // image == XCD
  int p = b >> 3;                                 // 0..63
  int h0 = (p >> 1)*4 + (p & 1);                  // rows h0, h0+2 cover all h
  int h2 = h0 + 2;
  int seg = wv * 16;

  // ---- resident K/V weight frags: wave<4 -> K strip wv (W2); wave>=4 -> V strip wv-4 (W3)
  int strip = wv & 3;
  const float* Wkv = (wv >= 4) ? W3 : W2;
  half8_t wf[4];
  #pragma unroll
  for (int k0 = 0; k0 < 4; ++k0) {
    int rb = (strip*16 + l15)*128 + k0*32 + q4*8;
    float4_t f0 = *(const float4_t*)&Wkv[rb];
    float4_t f1 = *(const float4_t*)&Wkv[rb + 4];
    #pragma unroll
    for (int j = 0; j < 4; ++j) { wf[k0][j] = (f16)f0[j]; wf[k0][j+4] = (f16)f1[j]; }
  }

  // ---- stage 64-px chunk c of x row into xs[px][136] f16 (float4 loads, 4x4 transpose)
  auto stage64 = [&](int row, int c) {
    int c4 = tid >> 4, pg = tid & 15;            // 32 ch-groups x 16 px-groups
    const float* xp = x + ((size_t)(n * CIN + c4 * 4) << 14) + (row << 7) + c * 64 + pg * 4;
    float4_t v0 = *(const float4_t*)xp;
    float4_t v1 = *(const float4_t*)(xp + 16384);
    float4_t v2 = *(const float4_t*)(xp + 32768);
    float4_t v3 = *(const float4_t*)(xp + 49152);
    #pragma unroll
    for (int i = 0; i < 4; ++i) {
      half4_t h = {(f16)v0[i], (f16)v1[i], (f16)v2[i], (f16)v3[i]};
      *(half4_t*)&xs[(pg * 4 + i) * 136 + c4 * 4] = h;
    }
  };

  // ================= prologue: Q for rows h0, h2 -> aq frags =================
  half8_t aq0[2], aq1[2];
  #pragma unroll
  for (int rr = 0; rr < 2; ++rr) {
    int row = rr ? h2 : h0;
    #pragma unroll
    for (int c = 0; c < 2; ++c) {
      __syncthreads();
      stage64(row, c);
      __syncthreads();
      if ((wv >> 2) == c) {                      // waves of this chunk conv Q (all 4 strips)
        int mt = wv & 3;
        #pragma unroll
        for (int s = 0; s < 4; ++s) {
          half8_t wq[4];
          #pragma unroll
          for (int k0 = 0; k0 < 4; ++k0) {
            int rb = (s*16 + l15)*128 + k0*32 + q4*8;
            float4_t f0 = *(const float4_t*)&W1[rb];
            float4_t f1 = *(const float4_t*)&W1[rb + 4];
            #pragma unroll
            for (int j = 0; j < 4; ++j) {
              wq[k0][j]   = (f16)(f0[j] * LOG2E);
              wq[k0][j+4] = (f16)(f1[j] * LOG2E);
            }
          }
          float4_t a = {0.f,0.f,0.f,0.f};
          #pragma unroll
          for (int k0 = 0; k0 < 4; ++k0) {
            half8_t xa = *(half8_t*)&xs[(mt*16 + l15)*136 + k0*32 + q4*8];
            a = __builtin_amdgcn_mfma_f32_16x16x32_f16(wq[k0], xa, a, 0, 0, 0); // D[cout][px]
          }
          int g = s*2 + (q4 >> 1);
          int px = wv*16 + l15;                  // = c*64 + mt*16 + l15
          half4_t h = {(f16)a[0], (f16)a[1], (f16)a[2], (f16)a[3]};
          *(half4_t*)&Ql[(size_t)(g*128 + px)*8 + (q4 & 1)*4] = h;
        }
      }
    }
    __syncthreads();                             // Ql complete for this row
    half8_t a0 = *(half8_t*)&Ql[(size_t)((q4    )*128 + seg + l15)*8];
    half8_t a1 = *(half8_t*)&Ql[(size_t)((q4 + 4)*128 + seg + l15)*8];
    if (rr == 0) { aq0[0] = a0; aq0[1] = a1; }
    else         { aq1[0] = a0; aq1[1] = a1; }
  }
  __syncthreads();                               // aq reads done before Vl (alias) writes

  // ---- zero K/V px halos (slots 0..7, 136..143) once; interior rewritten per row
  if (tid < 128) {
    int g = tid >> 4, hp = tid & 15;
    int idx = (hp < 8) ? hp : 128 + hp;
    *(float4_t*)&Kl[(size_t)(g*144 + idx)*8] = (float4_t){0.f,0.f,0.f,0.f};
  }
  if (tid < 128) {
    int row = tid >> 1;
    int idx = (tid & 1) ? 136 : 0;
    *(float4_t*)&Vl[(size_t)row*144 + idx] = (float4_t){0.f,0.f,0.f,0.f};
  }

  // ---- dh-invariant validity bits (identical to verified kernel)
  unsigned vbits = 0;
  #pragma unroll
  for (int jt = 0; jt < 2; ++jt)
    #pragma unroll
    for (int rrr = 0; rrr < 4; ++rrr) {
      int jw = seg - 8 + jt*16 + q4*4 + rrr;
      int iw = seg + l15;
      int d  = jw - iw;
      bool val = (((d & 1) == 0) & (d >= -8) & (d <= 8) & ((unsigned)jw < 128u));
      vbits |= ((unsigned)val) << (jt*4 + rrr);
    }

  float s0 = 0.f, s1 = 0.f;
  float4_t o0[4], o1[4];
  #pragma unroll
  for (int ct = 0; ct < 4; ++ct) {
    o0[ct] = (float4_t){0.f,0.f,0.f,0.f};
    o1[ct] = (float4_t){0.f,0.f,0.f,0.f};
  }

  unsigned short* P = plds + wv * 640;           // shared between row0/row1 bodies

  auto row_body = [&](const half8_t* aq, float& s_part, float4_t* o,
                      const half8_t (&bk)[2][2], const bs8 (&bv)[4]) {
    float4_t st0 = (float4_t){0.f,0.f,0.f,0.f};
    float4_t st1 = (float4_t){0.f,0.f,0.f,0.f};
    st0 = __builtin_amdgcn_mfma_f32_16x16x32_f16(bk[0][0], aq[0], st0, 0, 0, 0);
    st0 = __builtin_amdgcn_mfma_f32_16x16x32_f16(bk[0][1], aq[1], st0, 0, 0, 0);
    st1 = __builtin_amdgcn_mfma_f32_16x16x32_f16(bk[1][0], aq[0], st1, 0, 0, 0);
    st1 = __builtin_amdgcn_mfma_f32_16x16x32_f16(bk[1][1], aq[1], st1, 0, 0, 0);
    #pragma unroll
    for (int r = 0; r < 4; ++r) {
      st0[r] = exp2f(((vbits >> r)       & 1u) ? st0[r] : -1e30f);
      st1[r] = exp2f(((vbits >> (4 + r)) & 1u) ? st1[r] : -1e30f);
    }
    s_part += (st0[0] + st0[1]) + (st0[2] + st0[3])
            + (st1[0] + st1[1]) + (st1[2] + st1[3]);
    uint2_t pk0, pk1;
    pk0.x = (__float_as_uint(st0[1]) & 0xffff0000u) | (__float_as_uint(st0[0]) >> 16);
    pk0.y = (__float_as_uint(st0[3]) & 0xffff0000u) | (__float_as_uint(st0[2]) >> 16);
    pk1.x = (__float_as_uint(st1[1]) & 0xffff0000u) | (__float_as_uint(st1[0]) >> 16);
    pk1.y = (__float_as_uint(st1[3]) & 0xffff0000u) | (__float_as_uint(st1[2]) >> 16);
    *(uint2_t*)&P[l15*40      + q4*4] = pk0;
    *(uint2_t*)&P[l15*40 + 16 + q4*4] = pk1;
    bs8 ap = *(bs8*)&P[l15*40 + q4*8];
    #pragma unroll
    for (int ct = 0; ct < 4; ++ct)
      o[ct] = __builtin_amdgcn_mfma_f32_16x16x32_bf16(ap, bv[ct], o[ct], 0, 0, 0);
  };

  // ================= main loop over K/V rows =================
  for (int hs = h0 - 8; hs <= h0 + 10; hs += 2) {
    if (hs < 0 || hs > 127) continue;            // block-uniform

    #pragma unroll
    for (int c = 0; c < 2; ++c) {
      __syncthreads();                           // prev readers of Kl/Vl (c=0) / xs (c=1) done
      stage64(hs, c);
      __syncthreads();
      if (wv < 4) {                              // K strip
        #pragma unroll
        for (int mt = 0; mt < 4; ++mt) {
          float4_t a = {0.f,0.f,0.f,0.f};
          #pragma unroll
          for (int k0 = 0; k0 < 4; ++k0) {
            half8_t xa = *(half8_t*)&xs[(mt*16 + l15)*136 + k0*32 + q4*8];
            a = __builtin_amdgcn_mfma_f32_16x16x32_f16(wf[k0], xa, a, 0, 0, 0); // D[cout][px]
          }
          int px = c*64 + mt*16 + l15;
          int g = strip*2 + (q4 >> 1);
          half4_t h = {(f16)a[0], (f16)a[1], (f16)a[2], (f16)a[3]};
          *(half4_t*)&Kl[(size_t)(g*144 + 8 + px)*8 + (q4 & 1)*4] = h;
        }
      } else {                                   // V strip
        #pragma unroll
        for (int mt = 0; mt < 4; ++mt) {
          float4_t a = {0.f,0.f,0.f,0.f};
          #pragma unroll
          for (int k0 = 0; k0 < 4; ++k0) {
            half8_t xa = *(half8_t*)&xs[(mt*16 + l15)*136 + k0*32 + q4*8];
            a = __builtin_amdgcn_mfma_f32_16x16x32_f16(xa, wf[k0], a, 0, 0, 0); // D[px][cout]
          }
          uint2_t pv;
          pv.x = (unsigned)f2bf(a[0]) | ((unsigned)f2bf(a[1]) << 16);
          pv.y = (unsigned)f2bf(a[2]) | ((unsigned)f2bf(a[3]) << 16);
          *(uint2_t*)&Vl[(size_t)(strip*16 + l15)*144 + 8 + c*64 + mt*16 + q4*4] = pv;
        }
      }
    }
    __syncthreads();                             // K/V row complete

    half8_t bk[2][2];
    #pragma unroll
    for (int jt = 0; jt < 2; ++jt) {
      bk[jt][0] = *(half8_t*)&Kl[(size_t)((q4    )*144 + seg + jt*16 + l15)*8];
      bk[jt][1] = *(half8_t*)&Kl[(size_t)((q4 + 4)*144 + seg + jt*16 + l15)*8];
    }
    bs8 bv[4];
    #pragma unroll
    for (int ct = 0; ct < 4; ++ct)
      bv[ct] = *(bs8*)&Vl[(size_t)(ct*16 + l15)*144 + seg + q4*8];

    if (hs <= h0 + 8) row_body(aq0, s0, o0, bk, bv);
    if (hs >= h2 - 8) row_body(aq1, s1, o1, bk, bv);
  }

  // ================= epilogue (unchanged) =================
  int iw = seg + l15;
  int wlo = iw - 8; if (wlo < 0) wlo = 0;
  int whi = iw + 8; if (whi > 127) whi = 127;
  int vw = ((whi - wlo) >> 1) + 1;
  #pragma unroll
  for (int row = 0; row < 2; ++row) {
    int hr = row ? h2 : h0;
    int hlo = hr - 8; if (hlo < 0) hlo = 0;
    int hhi = hr + 8; if (hhi > 127) hhi = 127;
    int vh = ((hhi - hlo) >> 1) + 1;
    float cnt = (float)(81 - vh * vw);
    float srow = row ? s1 : s0;
    srow += __shfl_xor(srow, 16, 64);
    srow += __shfl_xor(srow, 32, 64);
    float sc = 1.f / (srow + cnt);
    float4_t scv;
    #pragma unroll
    for (int r = 0; r < 4; ++r) scv[r] = __shfl(sc, q4*4 + r, 64);
    const float4_t* o = row ? o1 : o0;
    #pragma unroll
    for (int ct = 0; ct < 4; ++ct) {
      size_t ob = ((size_t)(n*COUT + ct*16 + l15) << 14) + (hr << 7) + seg + q4*4;
      float4_t stv;
      #pragma unroll
      for (int r = 0; r < 4; ++r) stv[r] = o[ct][r] * scv[r];
      *(float4_t*)&out[ob] = stv;
    }
  }
}

// ---------------- launcher ----------------
extern "C" void kernel_launch(void* const* d_in, const int* in_sizes, int n_in,
                              void* d_out, int out_size, void* d_ws, size_t ws_size,
                              hipStream_t stream)
{
  const float* x  = (const float*)d_in[0];
  const float* W1 = (const float*)d_in[1];
  const float* W2 = (const float*)d_in[2];
  const float* W3 = (const float*)d_in[3];
  float* outp = (float*)d_out;
  (void)d_ws; (void)ws_size;                      // no workspace: fully fused

  fused_k<<<NB * 128 / 2, 512, 0, stream>>>(x, W1, W2, W3, outp);
}

// Round 5
// 155.179 us; speedup vs baseline: 1.2505x; 1.2505x over previous
//
#include <hip/hip_runtime.h>
#include <cstdint>
#include <cstddef>

#define NB   8
#define CIN  128
#define COUT 64
#define NPIX 131072
#define PLANE NPIX
#define LOG2E 1.44269504088896340736f

typedef _Float16 f16;
typedef _Float16 half4_t __attribute__((ext_vector_type(4)));
typedef _Float16 half8_t __attribute__((ext_vector_type(8)));
typedef short    bs8    __attribute__((ext_vector_type(8)));  // bf16x8 frag (bit pattern)
typedef float    float4_t __attribute__((ext_vector_type(4)));
typedef unsigned int uint2_t __attribute__((ext_vector_type(2)));

// float -> bf16 bits, RNE
__device__ __forceinline__ unsigned short f2bf(float f){
  unsigned u = __float_as_uint(f);
  return (unsigned short)((u + 0x7fffu + ((u >> 16) & 1u)) >> 16);
}

// ============ Kernel 0: pack W1|W2|W3 -> f16 [192][128]; W1 pre-scaled by log2e ============
__global__ __launch_bounds__(256) void wsetup_k(
    const float* __restrict__ W1, const float* __restrict__ W2,
    const float* __restrict__ W3, f16* __restrict__ Wf)
{
  int idx = blockIdx.x * 256 + threadIdx.x;      // 0 .. 24575
  int mat = idx >> 13;
  int rem = idx & 8191;
  const float* src = (mat == 0 ? W1 : (mat == 1 ? W2 : W3));
  float v = src[rem];
  if (mat == 0) v *= LOG2E;                      // logits in base-2 -> exp2 in attn
  Wf[idx] = (f16)v;
}

// ============ Kernel 1: 1x1 convs, 128-px tile, double-buffered staging ============
// Block 256 = 4 waves, TWO 64-px chunks (A,B) per block, grid 1024. Pipeline:
//   loadA -> ldsA -> issue loadB -> sync -> computeA (48 MFMA+stores, hides B latency)
//   -> ldsB -> sync -> computeB.
// Conv was pinned ~41us across 3 variants with every pipe <27% (latency-bound,
// phase-serialized load->barrier->compute). This overlaps chunk-B HBM latency with
// chunk-A MFMA. W preload amortized over 2x px. MFMA/store code verbatim from R3.
__global__ __launch_bounds__(256, 4) void conv_mfma_k(
    const float* __restrict__ x, const f16* __restrict__ Wf,
    f16* __restrict__ Qi, f16* __restrict__ Ki, unsigned short* __restrict__ V2)
{
  __shared__ __align__(16) f16 xs[2][64 * 136];  // 34.8 KB -> 4 blocks/CU

  int tid = threadIdx.x, lane = tid & 63, wv = tid >> 6;
  int l15 = lane & 15, q4 = lane >> 4;
  int b = blockIdx.x;
  int vb = (b & 7) * 128 + (b >> 3);             // bijective; image n = b&7 = XCD n
  int pxt = vb * 128;
  int n = pxt >> 14, hwt = pxt & 16383;

  int pxi = lane & 15, cg = lane >> 4;           // px-group 0..15, channel sub-group 0..3

  // ---- prefetch loads for one 64-px chunk into registers (8x float4) ----
  float4_t pre[2][4];
  auto load_regs = [&](int co) {
    #pragma unroll
    for (int s = 0; s < 2; ++s) {
      int c4 = s * 16 + wv * 4 + cg;             // 4-channel group 0..31
      const float* xp = x + ((size_t)(n * CIN + c4 * 4) << 14) + hwt + co + pxi * 4;
      pre[s][0] = *(const float4_t*)(xp);
      pre[s][1] = *(const float4_t*)(xp + 16384);
      pre[s][2] = *(const float4_t*)(xp + 32768);
      pre[s][3] = *(const float4_t*)(xp + 49152);
    }
  };
  // ---- convert + write prefetched chunk into LDS buffer (4x4 transpose) ----
  auto write_lds = [&](int buf) {
    #pragma unroll
    for (int s = 0; s < 2; ++s) {
      int c4 = s * 16 + wv * 4 + cg;
      #pragma unroll
      for (int i = 0; i < 4; ++i) {
        half4_t h = { (f16)pre[s][0][i], (f16)pre[s][1][i],
                      (f16)pre[s][2][i], (f16)pre[s][3][i] };
        *(half4_t*)&xs[buf][(pxi * 4 + i) * 136 + c4 * 4] = h;
      }
    }
  };

  // preload W frags (f16, L2-hot; reused across both chunks)
  half8_t wq[4], wk[4], wvf[4];
  #pragma unroll
  for (int k0 = 0; k0 < 4; ++k0) {
    wq[k0]  = *(const half8_t*)&Wf[((wv     )*16 + l15)*128 + k0*32 + q4*8];
    wk[k0]  = *(const half8_t*)&Wf[((wv +  4)*16 + l15)*128 + k0*32 + q4*8];
    wvf[k0] = *(const half8_t*)&Wf[((wv +  8)*16 + l15)*128 + k0*32 + q4*8];
  }

  // ---- MFMA + store for one staged 64-px chunk ----
  auto compute = [&](int buf, int co) {
    #pragma unroll
    for (int mt = 0; mt < 4; ++mt) {
      float4_t cq = {0.f,0.f,0.f,0.f}, ck = {0.f,0.f,0.f,0.f}, cv = {0.f,0.f,0.f,0.f};
      #pragma unroll
      for (int k0 = 0; k0 < 4; ++k0) {
        half8_t xa = *(half8_t*)&xs[buf][(mt*16 + l15)*136 + k0*32 + q4*8];
        cq = __builtin_amdgcn_mfma_f32_16x16x32_f16(wq[k0],  xa, cq, 0, 0, 0); // D[cout][px]
        ck = __builtin_amdgcn_mfma_f32_16x16x32_f16(wk[k0],  xa, ck, 0, 0, 0); // D[cout][px]
        cv = __builtin_amdgcn_mfma_f32_16x16x32_f16(xa, wvf[k0], cv, 0, 0, 0); // D[px][cout]
      }
      int pxq = pxt + co + mt*16 + l15;          // Q/K: col = px
      int g   = wv*2 + (q4 >> 1);                // cout = wv*16 + q4*4 + r
      half4_t hq = {(f16)cq[0], (f16)cq[1], (f16)cq[2], (f16)cq[3]};
      half4_t hk = {(f16)ck[0], (f16)ck[1], (f16)ck[2], (f16)ck[3]};
      *(half4_t*)&Qi[((size_t)g * PLANE + pxq) * 8 + (q4 & 1)*4] = hq;
      *(half4_t*)&Ki[((size_t)g * PLANE + pxq) * 8 + (q4 & 1)*4] = hk;
      // V: planar bf16 [cout][px], row = px = q4*4+r (RNE pack)
      uint2_t pv;
      pv.x = (unsigned)f2bf(cv[0]) | ((unsigned)f2bf(cv[1]) << 16);
      pv.y = (unsigned)f2bf(cv[2]) | ((unsigned)f2bf(cv[3]) << 16);
      *(uint2_t*)&V2[(size_t)(wv*16 + l15) * PLANE + pxt + co + mt*16 + q4*4] = pv;
    }
  };

  // ---- pipelined schedule ----
  load_regs(0);            // chunk A
  write_lds(0);
  load_regs(64);           // chunk B issued; latency hidden under computeA
  __syncthreads();
  compute(0, 0);
  write_lds(1);            // waits on B loads
  __syncthreads();
  compute(1, 64);
}

// ============ Kernel 2: fused flash local attention, row-paired, NO-MAX softmax ============
// (verbatim from R3 -- verified, ~40us; next optimization target once conv confirms)
__global__ __launch_bounds__(512, 4) void attn_fused_k(
    const f16* __restrict__ Qi, const f16* __restrict__ Ki,
    const unsigned short* __restrict__ V2, float* __restrict__ out)
{
  __shared__ __align__(16) unsigned short plds[8][2][16 * 40];   // 20.5 KB

  int tid = threadIdx.x, lane = tid & 63, wv = tid >> 6;
  int l15 = lane & 15, q4 = lane >> 4;
  int b = blockIdx.x;
  int n = b & 7;                                  // XCD swizzle: image n -> XCD n
  int p = b >> 3;                                 // 0..63
  int h0 = (p >> 1)*4 + (p & 1);                  // rows h0, h0+2 cover all h
  int h2 = h0 + 2;
  int seg = wv * 16;
  int nb = n << 14;

  unsigned short* P0 = &plds[wv][0][0];
  unsigned short* P1 = &plds[wv][1][0];

  // Q B-frags for both rows (n-dim = i = l15)
  half8_t aq0[2], aq1[2];
  {
    int px0 = nb + (h0 << 7) + seg + l15;
    aq0[0] = *(const half8_t*)&Qi[((size_t)(q4    ) * PLANE + px0) * 8];
    aq0[1] = *(const half8_t*)&Qi[((size_t)(q4 + 4) * PLANE + px0) * 8];
    int px1 = px0 + 256;
    aq1[0] = *(const half8_t*)&Qi[((size_t)(q4    ) * PLANE + px1) * 8];
    aq1[1] = *(const half8_t*)&Qi[((size_t)(q4 + 4) * PLANE + px1) * 8];
  }

  // dh-invariant validity: bit jt*4+r; lane j = seg-8+jt*16+q4*4+r, i = seg+l15
  unsigned vbits = 0;
  #pragma unroll
  for (int jt = 0; jt < 2; ++jt)
    #pragma unroll
    for (int rr = 0; rr < 4; ++rr) {
      int jw = seg - 8 + jt*16 + q4*4 + rr;
      int iw = seg + l15;
      int d  = jw - iw;
      bool val = (((d & 1) == 0) & (d >= -8) & (d <= 8) & ((unsigned)jw < 128u));
      vbits |= ((unsigned)val) << (jt*4 + rr);
    }

  float s0 = 0.f, s1 = 0.f;                       // per-lane partial denominators
  float4_t o0[4], o1[4];
  #pragma unroll
  for (int ct = 0; ct < 4; ++ct) {
    o0[ct] = (float4_t){0.f,0.f,0.f,0.f};
    o1[ct] = (float4_t){0.f,0.f,0.f,0.f};
  }

  auto row_body = [&](const half8_t* aq, float& s_part,
                      float4_t* o, unsigned short* P,
                      const half8_t (&bk)[2][2], const bs8 (&bv)[4]) {
    float4_t st0 = (float4_t){0.f,0.f,0.f,0.f};
    float4_t st1 = (float4_t){0.f,0.f,0.f,0.f};
    st0 = __builtin_amdgcn_mfma_f32_16x16x32_f16(bk[0][0], aq[0], st0, 0, 0, 0);
    st0 = __builtin_amdgcn_mfma_f32_16x16x32_f16(bk[0][1], aq[1], st0, 0, 0, 0);
    st1 = __builtin_amdgcn_mfma_f32_16x16x32_f16(bk[1][0], aq[0], st1, 0, 0, 0);
    st1 = __builtin_amdgcn_mfma_f32_16x16x32_f16(bk[1][1], aq[1], st1, 0, 0, 0);
    // mask -> exp2 (masked lanes: exp2(-1e30) = 0)
    #pragma unroll
    for (int rr = 0; rr < 4; ++rr) {
      st0[rr] = exp2f(((vbits >> rr)       & 1u) ? st0[rr] : -1e30f);
      st1[rr] = exp2f(((vbits >> (4 + rr)) & 1u) ? st1[rr] : -1e30f);
    }
    s_part += (st0[0] + st0[1]) + (st0[2] + st0[3])
            + (st1[0] + st1[1]) + (st1[2] + st1[3]);
    // P -> bf16 trunc pack (bias cancels in num/den ratio), 2x b64 LDS writes
    uint2_t pk0, pk1;
    pk0.x = (__float_as_uint(st0[1]) & 0xffff0000u) | (__float_as_uint(st0[0]) >> 16);
    pk0.y = (__float_as_uint(st0[3]) & 0xffff0000u) | (__float_as_uint(st0[2]) >> 16);
    pk1.x = (__float_as_uint(st1[1]) & 0xffff0000u) | (__float_as_uint(st1[0]) >> 16);
    pk1.y = (__float_as_uint(st1[3]) & 0xffff0000u) | (__float_as_uint(st1[2]) >> 16);
    *(uint2_t*)&P[l15*40      + q4*4] = pk0;
    *(uint2_t*)&P[l15*40 + 16 + q4*4] = pk1;
    bs8 ap = *(bs8*)&P[l15*40 + q4*8];            // A-layout read (K=32 exact)
    #pragma unroll
    for (int ct = 0; ct < 4; ++ct)
      o[ct] = __builtin_amdgcn_mfma_f32_16x16x32_bf16(ap, bv[ct], o[ct], 0, 0, 0);
  };

  for (int hs = h0 - 8; hs <= h0 + 10; hs += 2) {
    if (hs < 0 || hs > 127) continue;              // wave-uniform
    int jbase = nb + (hs << 7) + seg - 8;          // +-128B overrun stays in ws, masked

    half8_t bk[2][2];
    #pragma unroll
    for (int jt = 0; jt < 2; ++jt) {
      int pxj = jbase + jt*16 + l15;
      bk[jt][0] = *(const half8_t*)&Ki[((size_t)(q4    ) * PLANE + pxj) * 8];
      bk[jt][1] = *(const half8_t*)&Ki[((size_t)(q4 + 4) * PLANE + pxj) * 8];
    }
    bs8 bv[4];
    #pragma unroll
    for (int ct = 0; ct < 4; ++ct)
      bv[ct] = *(const bs8*)&V2[(size_t)(ct*16 + l15) * PLANE + jbase + q4*8];

    if (hs <= h0 + 8) row_body(aq0, s0, o0, P0, bk, bv);
    if (hs >= h2 - 8) row_body(aq1, s1, o1, P1, bk, bv);
  }

  // epilogue: reduce s over q4, add OOB count, normalize, float4 store
  int iw = seg + l15;
  int wlo = iw - 8; if (wlo < 0) wlo = 0;
  int whi = iw + 8; if (whi > 127) whi = 127;
  int vw = ((whi - wlo) >> 1) + 1;
  #pragma unroll
  for (int row = 0; row < 2; ++row) {
    int hr = row ? h2 : h0;
    int hlo = hr - 8; if (hlo < 0) hlo = 0;
    int hhi = hr + 8; if (hhi > 127) hhi = 127;
    int vh = ((hhi - hlo) >> 1) + 1;
    float cnt = (float)(81 - vh * vw);
    float srow = row ? s1 : s0;
    srow += __shfl_xor(srow, 16, 64);
    srow += __shfl_xor(srow, 32, 64);              // row-sum for i = l15
    float sc = 1.f / (srow + cnt);
    float4_t scv;
    #pragma unroll
    for (int rr = 0; rr < 4; ++rr) scv[rr] = __shfl(sc, q4*4 + rr, 64);
    const float4_t* o = row ? o1 : o0;
    #pragma unroll
    for (int ct = 0; ct < 4; ++ct) {
      size_t ob = ((size_t)(n*COUT + ct*16 + l15) << 14) + (hr << 7) + seg + q4*4;
      float4_t stv;
      #pragma unroll
      for (int rr = 0; rr < 4; ++rr) stv[rr] = o[ct][rr] * scv[rr];
      *(float4_t*)&out[ob] = stv;
    }
  }
}

// ---------------- launcher ----------------
extern "C" void kernel_launch(void* const* d_in, const int* in_sizes, int n_in,
                              void* d_out, int out_size, void* d_ws, size_t ws_size,
                              hipStream_t stream)
{
  const float* x  = (const float*)d_in[0];
  const float* W1 = (const float*)d_in[1];
  const float* W2 = (const float*)d_in[2];
  const float* W3 = (const float*)d_in[3];

  // ws: Wf (48 KB, padded to 64 KB guard) | Qi | Ki | V2 (~48 MB of 268 MB).
  // +-128B edge overruns land in the guard / adjacent array, masked to zero weight.
  f16* Wf = (f16*)d_ws;                              // [192][128] f16
  f16* Qi = (f16*)((char*)d_ws + 65536);             // [8][PLANE][8] f16 interleaved
  f16* Ki = Qi + (size_t)8 * PLANE * 8;              // [8][PLANE][8] f16
  unsigned short* V2 = (unsigned short*)(Ki + (size_t)8 * PLANE * 8); // [64][PLANE] bf16

  float* outp = (float*)d_out;

  wsetup_k    <<<96,        256, 0, stream>>>(W1, W2, W3, Wf);
  conv_mfma_k <<<NPIX/128,  256, 0, stream>>>(x, Wf, Qi, Ki, V2);
  attn_fused_k<<<NB*128/2,  512, 0, stream>>>(Qi, Ki, V2, outp);
}